// Round 2
// baseline (3925.805 us; speedup 1.0000x reference)
//
#include <hip/hip_runtime.h>

#define BB  8
#define NP  2048
#define KNB 20
#define SS  (NP * KNB)   // 40960 spatial per batch for layers 1-4

typedef unsigned short bf16_t;

static __device__ __forceinline__ float bf2f(bf16_t u) {
    return __uint_as_float(((unsigned)u) << 16);
}
static __device__ __forceinline__ bf16_t f2bf(float f) {
    unsigned u = __float_as_uint(f);
    return (bf16_t)((u + 0x7fffu + ((u >> 16) & 1u)) >> 16);   // RNE
}

// ---- order-preserving float<->uint for atomicMax pooling ----
// key(x) monotone increasing; key==0 is below every finite float's key.
static __device__ __forceinline__ unsigned fkey(float f) {
    unsigned u = __float_as_uint(f);
    return (u & 0x80000000u) ? ~u : (u | 0x80000000u);
}
static __device__ __forceinline__ float funkey(unsigned k) {
    return (k & 0x80000000u) ? __uint_as_float(k ^ 0x80000000u) : __uint_as_float(~k);
}

template <typename T> struct V4;
template <> struct V4<float> {
    using t = float4;
    static __device__ __forceinline__ float4 cvt(float4 v) { return v; }
};
template <> struct V4<bf16_t> {
    using t = ushort4;
    static __device__ __forceinline__ float4 cvt(ushort4 v) {
        return make_float4(bf2f(v.x), bf2f(v.y), bf2f(v.z), bf2f(v.w));
    }
};

// ---- zero fill (pool keys + stats, contiguous region) ----
__global__ __launch_bounds__(256) void zero_kernel(float* __restrict__ p, int n4) {
    int t = blockIdx.x * 256 + threadIdx.x;
    if (t < n4) ((float4*)p)[t] = make_float4(0.f, 0.f, 0.f, 0.f);
}

// ---- kNN: top-20 by neg squared distance, matches jax.lax.top_k ordering ----
__global__ __launch_bounds__(256) void knn_kernel(const float* __restrict__ x,
                                                  int* __restrict__ idx) {
    __shared__ float4 tile[NP];   // (x0,x1,x2,||x||^2), 32 KiB
    int b = blockIdx.x >> 3;
    int i = ((blockIdx.x & 7) << 8) + threadIdx.x;
    const float* xb = x + (size_t)b * 3 * NP;
    for (int j = threadIdx.x; j < NP; j += 256) {
        float a0 = xb[j], a1 = xb[NP + j], a2 = xb[2 * NP + j];
        tile[j] = make_float4(a0, a1, a2, a0 * a0 + a1 * a1 + a2 * a2);
    }
    __syncthreads();
    float4 me = tile[i];
    float bv[KNB]; int bi[KNB];
#pragma unroll
    for (int k = 0; k < KNB; ++k) { bv[k] = -3.4e38f; bi[k] = 0; }
    for (int j = 0; j < NP; ++j) {
        float4 p = tile[j];
        float d = me.x * p.x + me.y * p.y + me.z * p.z;
        float v = 2.0f * d - me.w - p.w;
        if (v > bv[KNB - 1]) {
#pragma unroll
            for (int t = KNB - 1; t >= 0; --t) {
                float prev = (t > 0) ? bv[t - 1] : 3.4e38f;
                int   pri  = (t > 0) ? bi[t - 1] : 0;
                if (v > prev)       { bv[t] = prev; bi[t] = pri; }
                else if (v > bv[t]) { bv[t] = v;    bi[t] = j;   }
            }
        }
    }
    int* o = idx + ((size_t)b * NP + i) * KNB;
#pragma unroll
    for (int k = 0; k < KNB; ++k) o[k] = bi[k];
}

// ---- graph feature f[b, 0..5, n*K+k] = [nbr xyz, center xyz], bf16 ----
__global__ __launch_bounds__(256) void gather_kernel(const float* __restrict__ x,
                                                     const int* __restrict__ idx,
                                                     bf16_t* __restrict__ f) {
    int t = blockIdx.x * 256 + threadIdx.x;
    if (t >= BB * SS) return;
    int b = t / SS;
    int r = t - b * SS;
    int n = r / KNB;
    int j = idx[t];
    const float* xb = x + (size_t)b * 3 * NP;
    bf16_t* fb = f + (size_t)b * 6 * SS + r;
    fb[0]          = f2bf(xb[j]);
    fb[SS]         = f2bf(xb[NP + j]);
    fb[2 * SS]     = f2bf(xb[2 * NP + j]);
    fb[3 * SS]     = f2bf(xb[n]);
    fb[4 * SS]     = f2bf(xb[NP + n]);
    fb[5 * SS]     = f2bf(xb[2 * NP + n]);
}

// ---- tiled 1x1 conv. Block: 64 co x 256 s. Thread: 16 co x 4 s.
//      INBN: input h = relu(a*raw + d) applied on load (prev layer's BN).
//      POOL: fused max-over-k (pre-BN, valid since BN scale > 0) via
//            wave group-reduce + atomicMax on order-preserving keys.
//      Always: per-channel sum/sumsq stats via wave reduce + atomicAdd.
template <typename TIN, typename TOUT, bool INBN, bool POOL, bool STORE>
__global__ __launch_bounds__(256) void conv_tiled(
    const TIN* __restrict__ H, const float* __restrict__ Wt,
    const float* __restrict__ abin,
    TOUT* __restrict__ Y, unsigned* __restrict__ Mx, int chofs,
    float* __restrict__ stats, int Cin, int Cout, int Ssz) {
    __shared__ __align__(16) float wl[16][64];
    const int tid = threadIdx.x;
    const int sx  = tid & 63;        // lane (wave == co-subtile: cs uniform/wave)
    const int cs  = tid >> 6;
    const int s0  = blockIdx.x * 256 + sx * 4;
    const int cob = blockIdx.y * 64;
    const int b   = blockIdx.z;

    const TIN* h = H + (size_t)b * Cin * Ssz + s0;
    float acc[16][4];
#pragma unroll
    for (int r = 0; r < 16; ++r)
#pragma unroll
        for (int u = 0; u < 4; ++u) acc[r][u] = 0.f;

    auto body = [&](int c0, int cc) {
        typename V4<TIN>::t raw = *(const typename V4<TIN>::t*)(h + (size_t)(c0 + cc) * Ssz);
        float4 hv = V4<TIN>::cvt(raw);
        if constexpr (INBN) {
            float a = abin[c0 + cc], d = abin[Cin + c0 + cc];
            hv.x = fmaxf(fmaf(a, hv.x, d), 0.f);
            hv.y = fmaxf(fmaf(a, hv.y, d), 0.f);
            hv.z = fmaxf(fmaf(a, hv.z, d), 0.f);
            hv.w = fmaxf(fmaf(a, hv.w, d), 0.f);
        }
        const float4* wp = (const float4*)(&wl[cc][cs << 4]);
#pragma unroll
        for (int rq = 0; rq < 4; ++rq) {
            float4 wv = wp[rq];
            float wj[4] = {wv.x, wv.y, wv.z, wv.w};
#pragma unroll
            for (int j = 0; j < 4; ++j) {
                int r = (rq << 2) + j;
                acc[r][0] = fmaf(wj[j], hv.x, acc[r][0]);
                acc[r][1] = fmaf(wj[j], hv.y, acc[r][1]);
                acc[r][2] = fmaf(wj[j], hv.z, acc[r][2]);
                acc[r][3] = fmaf(wj[j], hv.w, acc[r][3]);
            }
        }
    };

    int c0 = 0;
    for (; c0 + 16 <= Cin; c0 += 16) {
        __syncthreads();
        for (int e = tid; e < (16 << 6); e += 256) {
            int cc = e >> 6, co = e & 63;
            wl[cc][co] = Wt[(size_t)(cob + co) * Cin + (c0 + cc)];
        }
        __syncthreads();
#pragma unroll
        for (int cc = 0; cc < 16; ++cc) body(c0, cc);
    }
    if (c0 < Cin) {
        const int chunk = Cin - c0;
        __syncthreads();
        for (int e = tid; e < (chunk << 6); e += 256) {
            int cc = e >> 6, co = e & 63;
            wl[cc][co] = Wt[(size_t)(cob + co) * Cin + (c0 + cc)];
        }
        __syncthreads();
        for (int cc = 0; cc < chunk; ++cc) body(c0, cc);
    }

    if constexpr (STORE) {
        TOUT* y = Y + ((size_t)b * Cout + cob + (cs << 4)) * Ssz + s0;
#pragma unroll
        for (int r = 0; r < 16; ++r) {
            if constexpr (sizeof(TOUT) == 2) {
                ushort4 o;
                o.x = f2bf(acc[r][0]); o.y = f2bf(acc[r][1]);
                o.z = f2bf(acc[r][2]); o.w = f2bf(acc[r][3]);
                *(ushort4*)((bf16_t*)y + (size_t)r * Ssz) = o;
            } else {
                *(float4*)((float*)y + (size_t)r * Ssz) =
                    make_float4(acc[r][0], acc[r][1], acc[r][2], acc[r][3]);
            }
        }
    }

    if constexpr (POOL) {
        const int n = s0 / KNB;           // 4 cols of a thread share one n
        int pn = __shfl_up(n, 1, 64);
        bool leader = (sx == 0) || (pn != n);
#pragma unroll
        for (int r = 0; r < 16; ++r) {
            float m = fmaxf(fmaxf(acc[r][0], acc[r][1]), fmaxf(acc[r][2], acc[r][3]));
#pragma unroll
            for (int o = 1; o <= 4; ++o) {   // group = <=5 consecutive lanes
                float om = __shfl_down(m, o, 64);
                int   on = __shfl_down(n, o, 64);
                if (on == n) m = fmaxf(m, om);
            }
            if (leader)
                atomicMax(&Mx[((size_t)b * 512 + chofs + cob + (cs << 4) + r) * NP + n],
                          fkey(m));
        }
    }

    // BN stats: wave reduce (wave == one 16-co subtile), then atomicAdd
#pragma unroll
    for (int r = 0; r < 16; ++r) {
        float sv = acc[r][0] + acc[r][1] + acc[r][2] + acc[r][3];
        float qv = acc[r][0] * acc[r][0] + acc[r][1] * acc[r][1] +
                   acc[r][2] * acc[r][2] + acc[r][3] * acc[r][3];
#pragma unroll
        for (int msk = 1; msk < 64; msk <<= 1) {
            sv += __shfl_xor(sv, msk, 64);
            qv += __shfl_xor(qv, msk, 64);
        }
        if (sx == 0) {
            atomicAdd(&stats[cob + (cs << 4) + r], sv);
            atomicAdd(&stats[Cout + cob + (cs << 4) + r], qv);
        }
    }
}

// ---- stats -> affine coefs: a = g*rsqrt(var+eps), d = b - mean*a ----
__global__ void bn_finalize_kernel(const float* __restrict__ stats,
                                   const float* __restrict__ g,
                                   const float* __restrict__ bt,
                                   float* __restrict__ ab, int C, float invM) {
    int c = blockIdx.x * 64 + threadIdx.x;
    if (c >= C) return;
    float mean = stats[c] * invM;
    float var  = fmaxf(stats[C + c] * invM - mean * mean, 0.f);
    float a = g[c] * rsqrtf(var + 1e-5f);
    ab[c] = a;
    ab[C + c] = fmaf(-mean, a, bt[c]);
}

// ---- decode pooled-max key, apply BN+ReLU, write float into xcat ----
__global__ __launch_bounds__(256) void pool_convert_kernel(float* __restrict__ xc,
                                                           const float* __restrict__ ab,
                                                           int C, int chofs) {
    int t = blockIdx.x * 256 + threadIdx.x;   // exact grid over B*C*NP
    int n = t & (NP - 1);
    int bc = t >> 11;
    int c = bc % C;
    int b = bc / C;
    size_t p = ((size_t)b * 512 + chofs + c) * NP + n;
    unsigned k = ((unsigned*)xc)[p];
    float f = funkey(k);
    xc[p] = fmaxf(fmaf(ab[c], f, ab[C + c]), 0.f);
}

// ---- final BN+ReLU + pad channels 512..1023 with zeros ----
__global__ __launch_bounds__(256) void out_kernel(const float* __restrict__ y5,
                                                  const float* __restrict__ ab,
                                                  float* __restrict__ out) {
    size_t t = ((size_t)blockIdx.x * 256 + threadIdx.x) * 4;
    int n  = (int)(t & (NP - 1));
    int bc = (int)(t >> 11);
    int c = bc & 1023;
    int b = bc >> 10;
    float4 v = make_float4(0.f, 0.f, 0.f, 0.f);
    if (c < 512) {
        float a = ab[c], d = ab[512 + c];
        float4 yv = *(const float4*)(y5 + ((size_t)b * 512 + c) * NP + n);
        v.x = fmaxf(fmaf(a, yv.x, d), 0.f);
        v.y = fmaxf(fmaf(a, yv.y, d), 0.f);
        v.z = fmaxf(fmaf(a, yv.z, d), 0.f);
        v.w = fmaxf(fmaf(a, yv.w, d), 0.f);
    }
    *(float4*)(out + t) = v;
}

extern "C" void kernel_launch(void* const* d_in, const int* in_sizes, int n_in,
                              void* d_out, int out_size, void* d_ws, size_t ws_size,
                              hipStream_t stream) {
    (void)in_sizes; (void)n_in; (void)out_size; (void)ws_size;
    const float* x  = (const float*)d_in[0];
    const float* W1 = (const float*)d_in[1];
    const float* W2 = (const float*)d_in[2];
    const float* W3 = (const float*)d_in[3];
    const float* W4 = (const float*)d_in[4];
    const float* W5 = (const float*)d_in[5];
    const float* g1 = (const float*)d_in[6];  const float* b1 = (const float*)d_in[7];
    const float* g2 = (const float*)d_in[8];  const float* b2 = (const float*)d_in[9];
    const float* g3 = (const float*)d_in[10]; const float* b3 = (const float*)d_in[11];
    const float* g4 = (const float*)d_in[12]; const float* b4 = (const float*)d_in[13];
    const float* g5 = (const float*)d_in[14]; const float* b5 = (const float*)d_in[15];

    // ---- workspace layout, ~153 MiB total, lifetime-aliased ----
    // arena [0, 125829120):
    //   f  (bf16  3.93MB) @ 0            live: gather..conv1
    //   y1 (bf16 41.9MB)  @ 4194304      live: conv1..conv2
    //   y2 (bf16 41.9MB)  @ 83886080     live: conv2..conv3
    //   y3 (bf16 83.9MB)  @ 0            live: conv3..conv4 (over dead f,y1)
    //   y5 (fp32 33.6MB)  @ 0            live: conv5..out   (over dead y3)
    // xcat (fp32 33.6MB) @ 125829120     pool keys -> pooled cat, live whole run
    // st   (8KB)         @ 159383552     contiguous after xcat (one zero pass)
    // ab   (8KB)         @ 159391744
    // idx  (1.3MB)       @ 159399936
    char* ws = (char*)d_ws;
    bf16_t* f    = (bf16_t*)(ws + 0);
    bf16_t* y1   = (bf16_t*)(ws + 4194304);
    bf16_t* y3   = (bf16_t*)(ws + 0);
    bf16_t* y2   = (bf16_t*)(ws + 83886080);
    float*  y5   = (float*) (ws + 0);
    float*  xcat = (float*) (ws + 125829120);
    float*  st   = (float*) (ws + 159383552);
    float*  ab   = (float*) (ws + 159391744);
    int*    idx  = (int*)   (ws + 159399936);

    float* st1 = st;        float* ab1 = ab;
    float* st2 = st + 128;  float* ab2 = ab + 128;
    float* st3 = st + 256;  float* ab3 = ab + 256;
    float* st4 = st + 512;  float* ab4 = ab + 512;
    float* st5 = st + 1024; float* ab5 = ab + 1024;

    const float invM14 = 1.f / (float)(BB * SS);   // 1/327680
    const float invM5  = 1.f / (float)(BB * NP);   // 1/16384

    // zero pool keys (xcat) + stats in one pass (contiguous, 2097664 float4s)
    zero_kernel<<<8194, 256, 0, stream>>>(xcat, 2097664);
    knn_kernel<<<64, 256, 0, stream>>>(x, idx);
    gather_kernel<<<1280, 256, 0, stream>>>(x, idx, f);

    // L1: 6 -> 64 (no input BN)
    conv_tiled<bf16_t, bf16_t, false, true, true><<<dim3(160, 1, 8), 256, 0, stream>>>(
        f, W1, nullptr, y1, (unsigned*)xcat, 0, st1, 6, 64, SS);
    bn_finalize_kernel<<<1, 64, 0, stream>>>(st1, g1, b1, ab1, 64, invM14);
    pool_convert_kernel<<<4096, 256, 0, stream>>>(xcat, ab1, 64, 0);

    // L2: 64 -> 64 (BN1 applied on load)
    conv_tiled<bf16_t, bf16_t, true, true, true><<<dim3(160, 1, 8), 256, 0, stream>>>(
        y1, W2, ab1, y2, (unsigned*)xcat, 64, st2, 64, 64, SS);
    bn_finalize_kernel<<<1, 64, 0, stream>>>(st2, g2, b2, ab2, 64, invM14);
    pool_convert_kernel<<<4096, 256, 0, stream>>>(xcat, ab2, 64, 64);

    // L3: 64 -> 128
    conv_tiled<bf16_t, bf16_t, true, true, true><<<dim3(160, 2, 8), 256, 0, stream>>>(
        y2, W3, ab2, y3, (unsigned*)xcat, 128, st3, 64, 128, SS);
    bn_finalize_kernel<<<2, 64, 0, stream>>>(st3, g3, b3, ab3, 128, invM14);
    pool_convert_kernel<<<8192, 256, 0, stream>>>(xcat, ab3, 128, 128);

    // L4: 128 -> 256, pooled-only (y4 never materialized)
    conv_tiled<bf16_t, float, true, true, false><<<dim3(160, 4, 8), 256, 0, stream>>>(
        y3, W4, ab3, (float*)nullptr, (unsigned*)xcat, 256, st4, 128, 256, SS);
    bn_finalize_kernel<<<4, 64, 0, stream>>>(st4, g4, b4, ab4, 256, invM14);
    pool_convert_kernel<<<16384, 256, 0, stream>>>(xcat, ab4, 256, 256);

    // L5: 512 -> 512 over [B, 512, N] (input already post-BN floats)
    conv_tiled<float, float, false, false, true><<<dim3(8, 8, 8), 256, 0, stream>>>(
        xcat, W5, nullptr, y5, (unsigned*)nullptr, 0, st5, 512, 512, NP);
    bn_finalize_kernel<<<8, 64, 0, stream>>>(st5, g5, b5, ab5, 512, invM5);
    out_kernel<<<16384, 256, 0, stream>>>(y5, ab5, (float*)d_out);
}

// Round 3
// 2783.064 us; speedup vs baseline: 1.4106x; 1.4106x over previous
//
#include <hip/hip_runtime.h>

#define BB  8
#define NP  2048
#define KNB 20
#define SS  (NP * KNB)   // 40960 spatial per batch for layers 1-4

typedef unsigned short bf16_t;

static __device__ __forceinline__ float bf2f(bf16_t u) {
    return __uint_as_float(((unsigned)u) << 16);
}
static __device__ __forceinline__ bf16_t f2bf(float f) {
    unsigned u = __float_as_uint(f);
    return (bf16_t)((u + 0x7fffu + ((u >> 16) & 1u)) >> 16);   // RNE
}

// ---- order-preserving float<->uint for atomicMax pooling ----
static __device__ __forceinline__ unsigned fkey(float f) {
    unsigned u = __float_as_uint(f);
    return (u & 0x80000000u) ? ~u : (u | 0x80000000u);
}
static __device__ __forceinline__ float funkey(unsigned k) {
    return (k & 0x80000000u) ? __uint_as_float(k ^ 0x80000000u) : __uint_as_float(~k);
}

template <typename T> struct V4;
template <> struct V4<float> {
    using t = float4;
    static __device__ __forceinline__ float4 cvt(float4 v) { return v; }
};
template <> struct V4<bf16_t> {
    using t = ushort4;
    static __device__ __forceinline__ float4 cvt(ushort4 v) {
        return make_float4(bf2f(v.x), bf2f(v.y), bf2f(v.z), bf2f(v.w));
    }
};

// ---- zero fill (pool keys + stats, contiguous region) ----
__global__ __launch_bounds__(256) void zero_kernel(float* __restrict__ p, int n4) {
    int t = blockIdx.x * 256 + threadIdx.x;
    if (t < n4) ((float4*)p)[t] = make_float4(0.f, 0.f, 0.f, 0.f);
}

// ==== kNN v2: 16 points x 16 segments per block, top-20 in EXPLICIT scalar
//      registers (no arrays -> no scratch spill), 16-lane shfl merge. ====
// Per-point result identical to jax.lax.top_k(neg_dist, 20)[1] incl. stability
// (within segment: strict-> insertion keeps earlier j above on ties; across
// segments: argmax tie-break picks smaller j).

#define KDECL(t) float v##t = -3.4e38f; int j##t = 0;
#define KSTEP(t, p) \
    { if (v > v##p) { v##t = v##p; j##t = j##p; } \
      else if (v > v##t) { v##t = v; j##t = j; } }
#define KSHIFT(t, n) v##t = v##n; j##t = j##n;

__global__ __launch_bounds__(256) void knn_kernel(const float* __restrict__ x,
                                                  int* __restrict__ idx) {
    __shared__ float4 tile[2064];    // 2048 + swizzle pad (j + (j>>7)), 33 KB
    const int tid  = threadIdx.x;
    const int b    = blockIdx.x >> 7;     // 128 blocks per batch
    const int pblk = blockIdx.x & 127;
    const int pl   = tid >> 4;            // local point 0..15
    const int seg  = tid & 15;            // segment 0..15 (128 j's each)
    const int i    = pblk * 16 + pl;
    const float* xb = x + (size_t)b * 3 * NP;

    for (int j = tid; j < NP; j += 256) {
        float a0 = xb[j], a1 = xb[NP + j], a2 = xb[2 * NP + j];
        tile[j + (j >> 7)] = make_float4(a0, a1, a2, a0 * a0 + a1 * a1 + a2 * a2);
    }
    __syncthreads();
    const float4 me = tile[i + (i >> 7)];

    KDECL(0)  KDECL(1)  KDECL(2)  KDECL(3)  KDECL(4)
    KDECL(5)  KDECL(6)  KDECL(7)  KDECL(8)  KDECL(9)
    KDECL(10) KDECL(11) KDECL(12) KDECL(13) KDECL(14)
    KDECL(15) KDECL(16) KDECL(17) KDECL(18) KDECL(19)

    const int jbase = seg * 128;
    const float4* tseg = &tile[seg * 129];   // phys base for this segment
    for (int t = 0; t < 128; ++t) {
        float4 p = tseg[t];
        float d = me.x * p.x + me.y * p.y + me.z * p.z;
        float v = 2.0f * d - me.w - p.w;     // same formula as reference
        int j = jbase + t;
        if (v > v19) {
            KSTEP(19,18) KSTEP(18,17) KSTEP(17,16) KSTEP(16,15) KSTEP(15,14)
            KSTEP(14,13) KSTEP(13,12) KSTEP(12,11) KSTEP(11,10) KSTEP(10,9)
            KSTEP(9,8)   KSTEP(8,7)   KSTEP(7,6)   KSTEP(6,5)   KSTEP(5,4)
            KSTEP(4,3)   KSTEP(3,2)   KSTEP(2,1)   KSTEP(1,0)
            if (v > v0) { v0 = v; j0 = j; }
        }
    }

    // merge 16 sorted-desc lists of 20 across the 16 lanes of this point
    int* o = idx + ((size_t)b * NP + i) * KNB;
    float hv = v0; int hj = j0;
    for (int r = 0; r < KNB; ++r) {
        float mv = hv; int mj = hj;
#pragma unroll
        for (int s = 1; s <= 8; s <<= 1) {
            float ov = __shfl_xor(mv, s, 64);
            int   oj = __shfl_xor(mj, s, 64);
            if (ov > mv || (ov == mv && oj < mj)) { mv = ov; mj = oj; }
        }
        if (seg == 0) o[r] = mj;
        if (hv == mv && hj == mj) {          // unique winner pops (j unique)
            KSHIFT(0,1)   KSHIFT(1,2)   KSHIFT(2,3)   KSHIFT(3,4)   KSHIFT(4,5)
            KSHIFT(5,6)   KSHIFT(6,7)   KSHIFT(7,8)   KSHIFT(8,9)   KSHIFT(9,10)
            KSHIFT(10,11) KSHIFT(11,12) KSHIFT(12,13) KSHIFT(13,14) KSHIFT(14,15)
            KSHIFT(15,16) KSHIFT(16,17) KSHIFT(17,18) KSHIFT(18,19)
            v19 = -3.4e38f; j19 = 0;
        }
        hv = v0; hj = j0;
    }
}

// ---- graph feature f[b, 0..5, n*K+k] = [nbr xyz, center xyz], bf16 ----
__global__ __launch_bounds__(256) void gather_kernel(const float* __restrict__ x,
                                                     const int* __restrict__ idx,
                                                     bf16_t* __restrict__ f) {
    int t = blockIdx.x * 256 + threadIdx.x;
    if (t >= BB * SS) return;
    int b = t / SS;
    int r = t - b * SS;
    int n = r / KNB;
    int j = idx[t];
    const float* xb = x + (size_t)b * 3 * NP;
    bf16_t* fb = f + (size_t)b * 6 * SS + r;
    fb[0]          = f2bf(xb[j]);
    fb[SS]         = f2bf(xb[NP + j]);
    fb[2 * SS]     = f2bf(xb[2 * NP + j]);
    fb[3 * SS]     = f2bf(xb[n]);
    fb[4 * SS]     = f2bf(xb[NP + n]);
    fb[5 * SS]     = f2bf(xb[2 * NP + n]);
}

// ---- tiled 1x1 conv. Block: 64 co x 256 s. Thread: 16 co x 4 s.
//      INBN: input h = relu(a*raw + d) applied on load (prev layer's BN).
//      POOL: fused max-over-k (pre-BN, valid since BN scale > 0) via
//            wave group-reduce + atomicMax on order-preserving keys.
//      Always: per-channel sum/sumsq stats via wave reduce + atomicAdd.
template <typename TIN, typename TOUT, bool INBN, bool POOL, bool STORE>
__global__ __launch_bounds__(256) void conv_tiled(
    const TIN* __restrict__ H, const float* __restrict__ Wt,
    const float* __restrict__ abin,
    TOUT* __restrict__ Y, unsigned* __restrict__ Mx, int chofs,
    float* __restrict__ stats, int Cin, int Cout, int Ssz) {
    __shared__ __align__(16) float wl[16][64];
    const int tid = threadIdx.x;
    const int sx  = tid & 63;        // lane (wave == co-subtile: cs uniform/wave)
    const int cs  = tid >> 6;
    const int s0  = blockIdx.x * 256 + sx * 4;
    const int cob = blockIdx.y * 64;
    const int b   = blockIdx.z;

    const TIN* h = H + (size_t)b * Cin * Ssz + s0;
    float acc[16][4];
#pragma unroll
    for (int r = 0; r < 16; ++r)
#pragma unroll
        for (int u = 0; u < 4; ++u) acc[r][u] = 0.f;

    auto body = [&](int c0, int cc) {
        typename V4<TIN>::t raw = *(const typename V4<TIN>::t*)(h + (size_t)(c0 + cc) * Ssz);
        float4 hv = V4<TIN>::cvt(raw);
        if constexpr (INBN) {
            float a = abin[c0 + cc], d = abin[Cin + c0 + cc];
            hv.x = fmaxf(fmaf(a, hv.x, d), 0.f);
            hv.y = fmaxf(fmaf(a, hv.y, d), 0.f);
            hv.z = fmaxf(fmaf(a, hv.z, d), 0.f);
            hv.w = fmaxf(fmaf(a, hv.w, d), 0.f);
        }
        const float4* wp = (const float4*)(&wl[cc][cs << 4]);
#pragma unroll
        for (int rq = 0; rq < 4; ++rq) {
            float4 wv = wp[rq];
            float wj[4] = {wv.x, wv.y, wv.z, wv.w};
#pragma unroll
            for (int j = 0; j < 4; ++j) {
                int r = (rq << 2) + j;
                acc[r][0] = fmaf(wj[j], hv.x, acc[r][0]);
                acc[r][1] = fmaf(wj[j], hv.y, acc[r][1]);
                acc[r][2] = fmaf(wj[j], hv.z, acc[r][2]);
                acc[r][3] = fmaf(wj[j], hv.w, acc[r][3]);
            }
        }
    };

    int c0 = 0;
    for (; c0 + 16 <= Cin; c0 += 16) {
        __syncthreads();
        for (int e = tid; e < (16 << 6); e += 256) {
            int cc = e >> 6, co = e & 63;
            wl[cc][co] = Wt[(size_t)(cob + co) * Cin + (c0 + cc)];
        }
        __syncthreads();
#pragma unroll
        for (int cc = 0; cc < 16; ++cc) body(c0, cc);
    }
    if (c0 < Cin) {
        const int chunk = Cin - c0;
        __syncthreads();
        for (int e = tid; e < (chunk << 6); e += 256) {
            int cc = e >> 6, co = e & 63;
            wl[cc][co] = Wt[(size_t)(cob + co) * Cin + (c0 + cc)];
        }
        __syncthreads();
        for (int cc = 0; cc < chunk; ++cc) body(c0, cc);
    }

    if constexpr (STORE) {
        TOUT* y = Y + ((size_t)b * Cout + cob + (cs << 4)) * Ssz + s0;
#pragma unroll
        for (int r = 0; r < 16; ++r) {
            if constexpr (sizeof(TOUT) == 2) {
                ushort4 o;
                o.x = f2bf(acc[r][0]); o.y = f2bf(acc[r][1]);
                o.z = f2bf(acc[r][2]); o.w = f2bf(acc[r][3]);
                *(ushort4*)((bf16_t*)y + (size_t)r * Ssz) = o;
            } else {
                *(float4*)((float*)y + (size_t)r * Ssz) =
                    make_float4(acc[r][0], acc[r][1], acc[r][2], acc[r][3]);
            }
        }
    }

    if constexpr (POOL) {
        const int n = s0 / KNB;           // 4 cols of a thread share one n
        int pn = __shfl_up(n, 1, 64);
        bool leader = (sx == 0) || (pn != n);
#pragma unroll
        for (int r = 0; r < 16; ++r) {
            float m = fmaxf(fmaxf(acc[r][0], acc[r][1]), fmaxf(acc[r][2], acc[r][3]));
#pragma unroll
            for (int o = 1; o <= 4; ++o) {   // group = <=5 consecutive lanes
                float om = __shfl_down(m, o, 64);
                int   on = __shfl_down(n, o, 64);
                if (on == n) m = fmaxf(m, om);
            }
            if (leader)
                atomicMax(&Mx[((size_t)b * 512 + chofs + cob + (cs << 4) + r) * NP + n],
                          fkey(m));
        }
    }

    // BN stats: wave reduce (wave == one 16-co subtile), then atomicAdd
#pragma unroll
    for (int r = 0; r < 16; ++r) {
        float sv = acc[r][0] + acc[r][1] + acc[r][2] + acc[r][3];
        float qv = acc[r][0] * acc[r][0] + acc[r][1] * acc[r][1] +
                   acc[r][2] * acc[r][2] + acc[r][3] * acc[r][3];
#pragma unroll
        for (int msk = 1; msk < 64; msk <<= 1) {
            sv += __shfl_xor(sv, msk, 64);
            qv += __shfl_xor(qv, msk, 64);
        }
        if (sx == 0) {
            atomicAdd(&stats[cob + (cs << 4) + r], sv);
            atomicAdd(&stats[Cout + cob + (cs << 4) + r], qv);
        }
    }
}

// ---- stats -> affine coefs: a = g*rsqrt(var+eps), d = b - mean*a ----
__global__ void bn_finalize_kernel(const float* __restrict__ stats,
                                   const float* __restrict__ g,
                                   const float* __restrict__ bt,
                                   float* __restrict__ ab, int C, float invM) {
    int c = blockIdx.x * 64 + threadIdx.x;
    if (c >= C) return;
    float mean = stats[c] * invM;
    float var  = fmaxf(stats[C + c] * invM - mean * mean, 0.f);
    float a = g[c] * rsqrtf(var + 1e-5f);
    ab[c] = a;
    ab[C + c] = fmaf(-mean, a, bt[c]);
}

// ---- decode pooled-max key, apply BN+ReLU, write float into xcat ----
__global__ __launch_bounds__(256) void pool_convert_kernel(float* __restrict__ xc,
                                                           const float* __restrict__ ab,
                                                           int C, int chofs) {
    int t = blockIdx.x * 256 + threadIdx.x;   // exact grid over B*C*NP
    int n = t & (NP - 1);
    int bc = t >> 11;
    int c = bc % C;
    int b = bc / C;
    size_t p = ((size_t)b * 512 + chofs + c) * NP + n;
    unsigned k = ((unsigned*)xc)[p];
    float f = funkey(k);
    xc[p] = fmaxf(fmaf(ab[c], f, ab[C + c]), 0.f);
}

// ---- final BN+ReLU + pad channels 512..1023 with zeros ----
__global__ __launch_bounds__(256) void out_kernel(const float* __restrict__ y5,
                                                  const float* __restrict__ ab,
                                                  float* __restrict__ out) {
    size_t t = ((size_t)blockIdx.x * 256 + threadIdx.x) * 4;
    int n  = (int)(t & (NP - 1));
    int bc = (int)(t >> 11);
    int c = bc & 1023;
    int b = bc >> 10;
    float4 v = make_float4(0.f, 0.f, 0.f, 0.f);
    if (c < 512) {
        float a = ab[c], d = ab[512 + c];
        float4 yv = *(const float4*)(y5 + ((size_t)b * 512 + c) * NP + n);
        v.x = fmaxf(fmaf(a, yv.x, d), 0.f);
        v.y = fmaxf(fmaf(a, yv.y, d), 0.f);
        v.z = fmaxf(fmaf(a, yv.z, d), 0.f);
        v.w = fmaxf(fmaf(a, yv.w, d), 0.f);
    }
    *(float4*)(out + t) = v;
}

extern "C" void kernel_launch(void* const* d_in, const int* in_sizes, int n_in,
                              void* d_out, int out_size, void* d_ws, size_t ws_size,
                              hipStream_t stream) {
    (void)in_sizes; (void)n_in; (void)out_size; (void)ws_size;
    const float* x  = (const float*)d_in[0];
    const float* W1 = (const float*)d_in[1];
    const float* W2 = (const float*)d_in[2];
    const float* W3 = (const float*)d_in[3];
    const float* W4 = (const float*)d_in[4];
    const float* W5 = (const float*)d_in[5];
    const float* g1 = (const float*)d_in[6];  const float* b1 = (const float*)d_in[7];
    const float* g2 = (const float*)d_in[8];  const float* b2 = (const float*)d_in[9];
    const float* g3 = (const float*)d_in[10]; const float* b3 = (const float*)d_in[11];
    const float* g4 = (const float*)d_in[12]; const float* b4 = (const float*)d_in[13];
    const float* g5 = (const float*)d_in[14]; const float* b5 = (const float*)d_in[15];

    // ---- workspace layout, ~153 MiB total, lifetime-aliased ----
    char* ws = (char*)d_ws;
    bf16_t* f    = (bf16_t*)(ws + 0);
    bf16_t* y1   = (bf16_t*)(ws + 4194304);
    bf16_t* y3   = (bf16_t*)(ws + 0);
    bf16_t* y2   = (bf16_t*)(ws + 83886080);
    float*  y5   = (float*) (ws + 0);
    float*  xcat = (float*) (ws + 125829120);
    float*  st   = (float*) (ws + 159383552);
    float*  ab   = (float*) (ws + 159391744);
    int*    idx  = (int*)   (ws + 159399936);

    float* st1 = st;        float* ab1 = ab;
    float* st2 = st + 128;  float* ab2 = ab + 128;
    float* st3 = st + 256;  float* ab3 = ab + 256;
    float* st4 = st + 512;  float* ab4 = ab + 512;
    float* st5 = st + 1024; float* ab5 = ab + 1024;

    const float invM14 = 1.f / (float)(BB * SS);   // 1/327680
    const float invM5  = 1.f / (float)(BB * NP);   // 1/16384

    // zero pool keys (xcat) + stats in one pass (contiguous, 2097664 float4s)
    zero_kernel<<<8194, 256, 0, stream>>>(xcat, 2097664);
    knn_kernel<<<1024, 256, 0, stream>>>(x, idx);
    gather_kernel<<<1280, 256, 0, stream>>>(x, idx, f);

    // L1: 6 -> 64 (no input BN)
    conv_tiled<bf16_t, bf16_t, false, true, true><<<dim3(160, 1, 8), 256, 0, stream>>>(
        f, W1, nullptr, y1, (unsigned*)xcat, 0, st1, 6, 64, SS);
    bn_finalize_kernel<<<1, 64, 0, stream>>>(st1, g1, b1, ab1, 64, invM14);
    pool_convert_kernel<<<4096, 256, 0, stream>>>(xcat, ab1, 64, 0);

    // L2: 64 -> 64 (BN1 applied on load)
    conv_tiled<bf16_t, bf16_t, true, true, true><<<dim3(160, 1, 8), 256, 0, stream>>>(
        y1, W2, ab1, y2, (unsigned*)xcat, 64, st2, 64, 64, SS);
    bn_finalize_kernel<<<1, 64, 0, stream>>>(st2, g2, b2, ab2, 64, invM14);
    pool_convert_kernel<<<4096, 256, 0, stream>>>(xcat, ab2, 64, 64);

    // L3: 64 -> 128
    conv_tiled<bf16_t, bf16_t, true, true, true><<<dim3(160, 2, 8), 256, 0, stream>>>(
        y2, W3, ab2, y3, (unsigned*)xcat, 128, st3, 64, 128, SS);
    bn_finalize_kernel<<<2, 64, 0, stream>>>(st3, g3, b3, ab3, 128, invM14);
    pool_convert_kernel<<<8192, 256, 0, stream>>>(xcat, ab3, 128, 128);

    // L4: 128 -> 256, pooled-only (y4 never materialized)
    conv_tiled<bf16_t, float, true, true, false><<<dim3(160, 4, 8), 256, 0, stream>>>(
        y3, W4, ab3, (float*)nullptr, (unsigned*)xcat, 256, st4, 128, 256, SS);
    bn_finalize_kernel<<<4, 64, 0, stream>>>(st4, g4, b4, ab4, 256, invM14);
    pool_convert_kernel<<<16384, 256, 0, stream>>>(xcat, ab4, 256, 256);

    // L5: 512 -> 512 over [B, 512, N] (input already post-BN floats)
    conv_tiled<float, float, false, false, true><<<dim3(8, 8, 8), 256, 0, stream>>>(
        xcat, W5, nullptr, y5, (unsigned*)nullptr, 0, st5, 512, 512, NP);
    bn_finalize_kernel<<<8, 64, 0, stream>>>(st5, g5, b5, ab5, 512, invM5);
    out_kernel<<<16384, 256, 0, stream>>>(y5, ab5, (float*)d_out);
}